// Round 5
// baseline (716.935 us; speedup 1.0000x reference)
//
#include <hip/hip_runtime.h>
#include <hip/hip_bf16.h>

#define SCOPE 63
#define ROWS_PER_WAVE 64
#define WAVES_PER_BLOCK 2
#define BLOCK_THREADS (WAVES_PER_BLOCK * 64)
#define ROWS_PER_BLOCK (ROWS_PER_WAVE * WAVES_PER_BLOCK)
#define TILE_ELEMS (ROWS_PER_WAVE * SCOPE)   // 4032 floats = 16128 B per wave

// ---------------------------------------------------------------------------
// Kernel 1: compute the inverse filter g = IFFT( 1 / FFT(delta - f) ) in fp64.
// One block, 64 threads; O(63^2) work — negligible.
// ---------------------------------------------------------------------------
__global__ void compute_inverse_filter(const float* __restrict__ f,
                                       float* __restrict__ g) {
    __shared__ double hre[SCOPE];
    __shared__ double him[SCOPE];
    const double TWO_PI = 6.283185307179586476925286766559;
    int t = threadIdx.x;
    if (t < SCOPE) {
        // FF[t] = sum_n (delta[n] - f[n]) * exp(-i 2 pi t n / 63)
        double re = 0.0, im = 0.0;
        for (int n = 0; n < SCOPE; ++n) {
            double x = (n == 0 ? 1.0 : 0.0) - (double)f[n];
            double ang = -TWO_PI * (double)(t * n) / (double)SCOPE;
            re += x * cos(ang);
            im += x * sin(ang);
        }
        // H[t] = 1 / FF[t]
        double d = re * re + im * im;
        hre[t] = re / d;
        him[t] = -im / d;
    }
    __syncthreads();
    if (t < SCOPE) {
        // g[t] = (1/63) * sum_k Re( H[k] * exp(+i 2 pi k t / 63) )
        double acc = 0.0;
        for (int k = 0; k < SCOPE; ++k) {
            double ang = TWO_PI * (double)(k * t) / (double)SCOPE;
            acc += hre[k] * cos(ang) - him[k] * sin(ang);
        }
        g[t] = (float)(acc / (double)SCOPE);
    }
}

// ---------------------------------------------------------------------------
// Kernel 2: per-row circular convolution out[n] = sum_m g[m] * a[(n-m) mod 63]
// Each wave owns 64 contiguous rows; LDS staging for coalesced HBM access.
// ---------------------------------------------------------------------------
__global__ void __launch_bounds__(BLOCK_THREADS)
circ_conv_kernel(const float* __restrict__ A,
                 const float* __restrict__ G,
                 float* __restrict__ O) {
    __shared__ __align__(16) float tile[WAVES_PER_BLOCK][TILE_ELEMS];
    __shared__ float gs[SCOPE];

    const int tid  = threadIdx.x;
    const int wave = tid >> 6;
    const int lane = tid & 63;

    if (tid < SCOPE) gs[tid] = G[tid];

    const long long blockRow0 = (long long)blockIdx.x * ROWS_PER_BLOCK;
    const long long waveRow0  = blockRow0 + (long long)wave * ROWS_PER_WAVE;

    const float* __restrict__ src = A + waveRow0 * SCOPE;
    float* __restrict__ dst       = O + waveRow0 * SCOPE;
    float* w = tile[wave];

    // ---- stage 64 rows (4032 floats) into LDS, coalesced ----
    // 4032 floats = 960 float4 (15 rounds of 64 lanes) + 192 scalar floats.
    const float4* src4 = (const float4*)src;
    float4* w4 = (float4*)w;
#pragma unroll
    for (int it = 0; it < 15; ++it)
        w4[it * 64 + lane] = src4[it * 64 + lane];
#pragma unroll
    for (int it = 0; it < 3; ++it)
        w[3840 + it * 64 + lane] = src[3840 + it * 64 + lane];

    __syncthreads();   // also covers gs visibility

    // ---- each lane pulls its own row into registers ----
    // LDS addr = lane*63 + j; 63 coprime with 32 banks -> conflict-free.
    float a[SCOPE];
    float* myrow = w + lane * SCOPE;
#pragma unroll
    for (int j = 0; j < SCOPE; ++j) a[j] = myrow[j];

    // ---- circular convolution, fully unrolled, all-register ----
    float acc[SCOPE];
#pragma unroll
    for (int n = 0; n < SCOPE; ++n) acc[n] = 0.0f;

#pragma unroll
    for (int m = 0; m < SCOPE; ++m) {
        const float gm = gs[m];   // uniform LDS broadcast, hoisted per m
#pragma unroll
        for (int n = 0; n < SCOPE; ++n) {
            acc[n] += gm * a[(n - m + SCOPE) % SCOPE];
        }
    }

    __syncthreads();   // everyone done reading tile as input

    // ---- write results back through LDS for coalesced stores ----
#pragma unroll
    for (int n = 0; n < SCOPE; ++n) myrow[n] = acc[n];

    __syncthreads();

    float4* dst4 = (float4*)dst;
#pragma unroll
    for (int it = 0; it < 15; ++it)
        dst4[it * 64 + lane] = w4[it * 64 + lane];
#pragma unroll
    for (int it = 0; it < 3; ++it)
        dst[3840 + it * 64 + lane] = w[3840 + it * 64 + lane];
}

// ---------------------------------------------------------------------------
extern "C" void kernel_launch(void* const* d_in, const int* in_sizes, int n_in,
                              void* d_out, int out_size, void* d_ws, size_t ws_size,
                              hipStream_t stream) {
    const float* activations = (const float*)d_in[0];
    const float* filt        = (const float*)d_in[1];
    float* out               = (float*)d_out;
    float* g                 = (float*)d_ws;   // 63 floats of scratch

    hipLaunchKernelGGL(compute_inverse_filter, dim3(1), dim3(64), 0, stream,
                       filt, g);

    const long long total = (long long)in_sizes[0];
    const long long rows  = total / SCOPE;           // 524288
    const int blocks      = (int)(rows / ROWS_PER_BLOCK);  // 4096, exact

    hipLaunchKernelGGL(circ_conv_kernel, dim3(blocks), dim3(BLOCK_THREADS), 0,
                       stream, activations, g, out);
}

// Round 6
// 127.002 us; speedup vs baseline: 5.6451x; 5.6451x over previous
//
#include <hip/hip_runtime.h>
#include <hip/hip_bf16.h>

#define SCOPE 63
#define ROWS_PER_WAVE 64
#define WAVES_PER_BLOCK 2
#define BLOCK_THREADS (WAVES_PER_BLOCK * 64)
#define ROWS_PER_BLOCK (ROWS_PER_WAVE * WAVES_PER_BLOCK)
#define TILE_ELEMS (ROWS_PER_WAVE * SCOPE)   // 4032 floats = 16128 B per wave

// ---------------------------------------------------------------------------
// Kernel 1: compute the inverse filter g = IFFT( 1 / FFT(delta - f) ) in fp64.
// One block, 64 threads; O(63^2) work — negligible.
// ---------------------------------------------------------------------------
__global__ void compute_inverse_filter(const float* __restrict__ f,
                                       float* __restrict__ g) {
    __shared__ double hre[SCOPE];
    __shared__ double him[SCOPE];
    const double TWO_PI = 6.283185307179586476925286766559;
    int t = threadIdx.x;
    if (t < SCOPE) {
        double re = 0.0, im = 0.0;
        for (int n = 0; n < SCOPE; ++n) {
            double x = (n == 0 ? 1.0 : 0.0) - (double)f[n];
            double ang = -TWO_PI * (double)(t * n) / (double)SCOPE;
            re += x * cos(ang);
            im += x * sin(ang);
        }
        double d = re * re + im * im;
        hre[t] = re / d;
        him[t] = -im / d;
    }
    __syncthreads();
    if (t < SCOPE) {
        double acc = 0.0;
        for (int k = 0; k < SCOPE; ++k) {
            double ang = TWO_PI * (double)(k * t) / (double)SCOPE;
            acc += hre[k] * cos(ang) - him[k] * sin(ang);
        }
        g[t] = (float)(acc / (double)SCOPE);
    }
}

// ---------------------------------------------------------------------------
// Compile-time-unrolled helpers: every private-array index is a constant, so
// a[] / g[] are SROA'd into registers (rule #20: no runtime-indexed private
// arrays -> no scratch).
// ---------------------------------------------------------------------------
template <int J>
struct LoadArr {
    __device__ static inline void run(float (&d)[SCOPE], const float* __restrict__ s) {
        LoadArr<J - 1>::run(d, s);
        d[J] = s[J];
    }
};
template <>
struct LoadArr<-1> {
    __device__ static inline void run(float (&)[SCOPE], const float* __restrict__) {}
};

// Inner sum over m for fixed output index N:  sum_m g[m] * a[(N-m) mod 63]
template <int N, int M>
struct ConvSum {
    __device__ static inline float run(const float (&a)[SCOPE], const float (&g)[SCOPE]) {
        return ConvSum<N, M - 1>::run(a, g) + g[M] * a[(N - M + SCOPE) % SCOPE];
    }
};
template <int N>
struct ConvSum<N, -1> {
    __device__ static inline float run(const float (&)[SCOPE], const float (&)[SCOPE]) {
        return 0.0f;
    }
};

// Outer loop over output index N; each result is written to LDS immediately so
// the accumulator dies at once (nothing live across any barrier).
template <int N>
struct RowConv {
    __device__ static inline void run(float* __restrict__ myrow,
                                      const float (&a)[SCOPE], const float (&g)[SCOPE]) {
        RowConv<N - 1>::run(myrow, a, g);
        myrow[N] = ConvSum<N, SCOPE - 1>::run(a, g);
    }
};
template <>
struct RowConv<-1> {
    __device__ static inline void run(float* __restrict__,
                                      const float (&)[SCOPE], const float (&)[SCOPE]) {}
};

// ---------------------------------------------------------------------------
// Kernel 2: per-row circular convolution out[n] = sum_m g[m] * a[(n-m) mod 63]
// Each wave owns 64 contiguous rows; LDS staging for coalesced HBM access.
// Lane i's LDS row (myrow) is private to lane i during compute: cross-lane
// access happens only in the staging and store phases, so only two barriers.
// ---------------------------------------------------------------------------
__global__ void __launch_bounds__(BLOCK_THREADS, 2)
circ_conv_kernel(const float* __restrict__ A,
                 const float* __restrict__ G,
                 float* __restrict__ O) {
    __shared__ __align__(16) float tile[WAVES_PER_BLOCK][TILE_ELEMS];

    const int tid  = threadIdx.x;
    const int wave = tid >> 6;
    const int lane = tid & 63;

    const long long blockRow0 = (long long)blockIdx.x * ROWS_PER_BLOCK;
    const long long waveRow0  = blockRow0 + (long long)wave * ROWS_PER_WAVE;

    const float* __restrict__ src = A + waveRow0 * SCOPE;
    float* __restrict__ dst       = O + waveRow0 * SCOPE;
    float* w = tile[wave];

    // ---- stage 64 rows (4032 floats) into LDS, coalesced ----
    const float4* src4 = (const float4*)src;
    float4* w4 = (float4*)w;
#pragma unroll
    for (int it = 0; it < 15; ++it)
        w4[it * 64 + lane] = src4[it * 64 + lane];
#pragma unroll
    for (int it = 0; it < 3; ++it)
        w[3840 + it * 64 + lane] = src[3840 + it * 64 + lane];

    __syncthreads();

    // ---- filter into registers (uniform constant-index global loads) ----
    float g[SCOPE];
    LoadArr<SCOPE - 1>::run(g, G);

    // ---- lane's own row into registers (LDS stride 63: conflict-free) ----
    float a[SCOPE];
    float* myrow = w + lane * SCOPE;
    LoadArr<SCOPE - 1>::run(a, myrow);

    // ---- circular convolution; each out[n] written to LDS as produced ----
    RowConv<SCOPE - 1>::run(myrow, a, g);

    __syncthreads();   // all rows written; tile now holds outputs

    // ---- coalesced store ----
    float4* dst4 = (float4*)dst;
#pragma unroll
    for (int it = 0; it < 15; ++it)
        dst4[it * 64 + lane] = w4[it * 64 + lane];
#pragma unroll
    for (int it = 0; it < 3; ++it)
        dst[3840 + it * 64 + lane] = w[3840 + it * 64 + lane];
}

// ---------------------------------------------------------------------------
extern "C" void kernel_launch(void* const* d_in, const int* in_sizes, int n_in,
                              void* d_out, int out_size, void* d_ws, size_t ws_size,
                              hipStream_t stream) {
    const float* activations = (const float*)d_in[0];
    const float* filt        = (const float*)d_in[1];
    float* out               = (float*)d_out;
    float* g                 = (float*)d_ws;   // 63 floats of scratch

    hipLaunchKernelGGL(compute_inverse_filter, dim3(1), dim3(64), 0, stream,
                       filt, g);

    const long long total = (long long)in_sizes[0];
    const long long rows  = total / SCOPE;           // 524288
    const int blocks      = (int)(rows / ROWS_PER_BLOCK);  // 4096, exact

    hipLaunchKernelGGL(circ_conv_kernel, dim3(blocks), dim3(BLOCK_THREADS), 0,
                       stream, activations, g, out);
}

// Round 7
// 110.496 us; speedup vs baseline: 6.4883x; 1.1494x over previous
//
#include <hip/hip_runtime.h>
#include <hip/hip_bf16.h>

#define SCOPE 63
#define BLOCK_THREADS 64
#define ROWS_PER_BLOCK 64
#define TILE_ELEMS (ROWS_PER_BLOCK * SCOPE)   // 4032 floats = 16128 B

// ---------------------------------------------------------------------------
// Kernel 1: inverse filter g = IFFT( 1 / FFT(delta - f) ) in fp64. Negligible.
// ---------------------------------------------------------------------------
__global__ void compute_inverse_filter(const float* __restrict__ f,
                                       float* __restrict__ g) {
    __shared__ double hre[SCOPE];
    __shared__ double him[SCOPE];
    const double TWO_PI = 6.283185307179586476925286766559;
    int t = threadIdx.x;
    if (t < SCOPE) {
        double re = 0.0, im = 0.0;
        for (int n = 0; n < SCOPE; ++n) {
            double x = (n == 0 ? 1.0 : 0.0) - (double)f[n];
            double ang = -TWO_PI * (double)(t * n) / (double)SCOPE;
            re += x * cos(ang);
            im += x * sin(ang);
        }
        double d = re * re + im * im;
        hre[t] = re / d;
        him[t] = -im / d;
    }
    __syncthreads();
    if (t < SCOPE) {
        double acc = 0.0;
        for (int k = 0; k < SCOPE; ++k) {
            double ang = TWO_PI * (double)(k * t) / (double)SCOPE;
            acc += hre[k] * cos(ang) - him[k] * sin(ang);
        }
        g[t] = (float)(acc / (double)SCOPE);
    }
}

// ---------------------------------------------------------------------------
// Compile-time-unrolled helpers (static indices only -> SROA to registers).
// ---------------------------------------------------------------------------
template <int J>
struct LoadArr {
    __device__ static inline void run(float (&d)[SCOPE], const float* s) {
        LoadArr<J - 1>::run(d, s);
        d[J] = s[J];
    }
};
template <>
struct LoadArr<-1> {
    __device__ static inline void run(float (&)[SCOPE], const float*) {}
};

template <int J>
struct StoreArr {
    __device__ static inline void run(float* d, const float (&s)[SCOPE]) {
        StoreArr<J - 1>::run(d, s);
        d[J] = s[J];
    }
};
template <>
struct StoreArr<-1> {
    __device__ static inline void run(float*, const float (&)[SCOPE]) {}
};

// acc[n] = g[0] * a[n]   (m = 0 initialization)
template <int N>
struct InitAcc {
    __device__ static inline void run(float (&acc)[SCOPE], const float (&a)[SCOPE],
                                      const float (&g)[SCOPE]) {
        InitAcc<N - 1>::run(acc, a, g);
        acc[N] = g[0] * a[N];
    }
};
template <>
struct InitAcc<-1> {
    __device__ static inline void run(float (&)[SCOPE], const float (&)[SCOPE],
                                      const float (&)[SCOPE]) {}
};

// For fixed M: acc[n] += g[M] * a[(n - M) mod 63], all n  (63 independent FMAs
// -> dependency distance 63 between reuses of the same acc[n]: full ILP)
template <int M, int N>
struct ConvRow {
    __device__ static inline void run(float (&acc)[SCOPE], const float (&a)[SCOPE],
                                      const float (&g)[SCOPE]) {
        ConvRow<M, N - 1>::run(acc, a, g);
        acc[N] += g[M] * a[(N - M + SCOPE) % SCOPE];
    }
};
template <int M>
struct ConvRow<M, -1> {
    __device__ static inline void run(float (&)[SCOPE], const float (&)[SCOPE],
                                      const float (&)[SCOPE]) {}
};

template <int M>
struct ConvOuter {
    __device__ static inline void run(float (&acc)[SCOPE], const float (&a)[SCOPE],
                                      const float (&g)[SCOPE]) {
        ConvOuter<M - 1>::run(acc, a, g);
        ConvRow<M, SCOPE - 1>::run(acc, a, g);
    }
};
template <>
struct ConvOuter<0> {
    __device__ static inline void run(float (&acc)[SCOPE], const float (&a)[SCOPE],
                                      const float (&g)[SCOPE]) {
        InitAcc<SCOPE - 1>::run(acc, a, g);
    }
};

// ---------------------------------------------------------------------------
// Kernel 2: per-row circular convolution. One wave per block, 64 rows/block.
// m-outer register accumulation; no barrier while acc[] is live.
// __launch_bounds__(64,2): VGPR cap 256 -> no spill for ~150 live regs.
// ---------------------------------------------------------------------------
__global__ void __launch_bounds__(BLOCK_THREADS, 2)
circ_conv_kernel(const float* __restrict__ A,
                 const float* __restrict__ G,
                 float* __restrict__ O) {
    __shared__ __align__(16) float tile[TILE_ELEMS];

    const int lane = threadIdx.x;   // 1 wave per block

    const long long row0 = (long long)blockIdx.x * ROWS_PER_BLOCK;
    const float* __restrict__ src = A + row0 * SCOPE;
    float* __restrict__ dst       = O + row0 * SCOPE;

    // ---- stage 64 rows (4032 floats) into LDS, coalesced ----
    const float4* src4 = (const float4*)src;
    float4* w4 = (float4*)tile;
#pragma unroll
    for (int it = 0; it < 15; ++it)
        w4[it * 64 + lane] = src4[it * 64 + lane];
#pragma unroll
    for (int it = 0; it < 3; ++it)
        tile[3840 + it * 64 + lane] = src[3840 + it * 64 + lane];

    __syncthreads();   // single wave: compiles to waitcnt only

    // ---- filter into registers; g is wave-uniform -> SGPR operands ----
    float g[SCOPE];
    LoadArr<SCOPE - 1>::run(g, G);

    // ---- lane's own row (LDS stride 63 floats: conflict-free) ----
    float a[SCOPE];
    float* myrow = tile + lane * SCOPE;
    LoadArr<SCOPE - 1>::run(a, myrow);

    // ---- m-outer circular convolution, acc[] fully in registers ----
    float acc[SCOPE];
    ConvOuter<SCOPE - 1>::run(acc, a, g);

    // ---- write results to own LDS row (lane-private; no barrier needed) ----
    StoreArr<SCOPE - 1>::run(myrow, acc);

    __syncthreads();

    // ---- coalesced store ----
    float4* dst4 = (float4*)dst;
#pragma unroll
    for (int it = 0; it < 15; ++it)
        dst4[it * 64 + lane] = w4[it * 64 + lane];
#pragma unroll
    for (int it = 0; it < 3; ++it)
        dst[3840 + it * 64 + lane] = tile[3840 + it * 64 + lane];
}

// ---------------------------------------------------------------------------
extern "C" void kernel_launch(void* const* d_in, const int* in_sizes, int n_in,
                              void* d_out, int out_size, void* d_ws, size_t ws_size,
                              hipStream_t stream) {
    const float* activations = (const float*)d_in[0];
    const float* filt        = (const float*)d_in[1];
    float* out               = (float*)d_out;
    float* g                 = (float*)d_ws;   // 63 floats of scratch

    hipLaunchKernelGGL(compute_inverse_filter, dim3(1), dim3(64), 0, stream,
                       filt, g);

    const long long total = (long long)in_sizes[0];
    const long long rows  = total / SCOPE;                 // 524288
    const int blocks      = (int)(rows / ROWS_PER_BLOCK);  // 8192, exact

    hipLaunchKernelGGL(circ_conv_kernel, dim3(blocks), dim3(BLOCK_THREADS), 0,
                       stream, activations, g, out);
}